// Round 15
// baseline (583.025 us; speedup 1.0000x reference)
//
#include <hip/hip_runtime.h>
#include <hip/hip_bf16.h>
#include <hip/hip_fp16.h>

// APPNP propagation on MI355X.
// R1:  parallel scan; float4 quarter-wave propagate.                690us
// R3:  fp16 intermediate h + 8-way edge parallelism.                586us
// R14: int2 bucket revert + fp16 feat0.                             582us
// R15: z-recurrence (z = norm*h): z_{t+1} = 0.9*norm^2 * sum z[src] + 0.1*z0.
//      Per-edge weight eliminated -> 4B src scatter, pure gather-sum loop.
//      Bucket split into 2 half dispatches so propagate shows in rocprof top-5.

#define D_FEAT 64
#define K_ITERS 10
#define ALPHA 0.1f

#define SCAN_THREADS 4096   // 16 blocks x 256
#define SCAN_BLOCKS  16

// ---------------------------------------------------------------- degree count
__global__ void count_deg_kernel(const int* __restrict__ dst, int* __restrict__ deg, int e) {
    int i = blockIdx.x * blockDim.x + threadIdx.x;
    if (i < e) atomicAdd(&deg[dst[i]], 1);
}

// ------------------------------------------------------- scan stage 1: partials
__global__ void partial_sum_kernel(const int* __restrict__ deg, int* __restrict__ tsums, int n) {
    int t = blockIdx.x * blockDim.x + threadIdx.x;        // 0..4095
    int chunk = (n + SCAN_THREADS - 1) / SCAN_THREADS;
    int beg = t * chunk, end = min(beg + chunk, n);
    int s = 0;
    for (int i = beg; i < end; ++i) s += deg[i];
    tsums[t] = s;
}

// -------------------------------------------- scan stage 2: scan 4096 partials
__global__ void scan_partials_kernel(int* __restrict__ tsums) {
    __shared__ int part[1024];
    const int tid = threadIdx.x;
    int s0 = tsums[tid * 4 + 0], s1 = tsums[tid * 4 + 1];
    int s2 = tsums[tid * 4 + 2], s3 = tsums[tid * 4 + 3];
    int sum = s0 + s1 + s2 + s3;
    part[tid] = sum;
    __syncthreads();
    for (int off = 1; off < 1024; off <<= 1) {
        int t = (tid >= off) ? part[tid - off] : 0;
        __syncthreads();
        part[tid] += t;
        __syncthreads();
    }
    int ex = part[tid] - sum;
    tsums[tid * 4 + 0] = ex;
    tsums[tid * 4 + 1] = ex + s0;
    tsums[tid * 4 + 2] = ex + s0 + s1;
    tsums[tid * 4 + 3] = ex + s0 + s1 + s2;
}

// --------------------------------- scan stage 3: row_ptr + norm + 0.9*norm^2
__global__ void write_rowptr_kernel(const int* __restrict__ deg, const int* __restrict__ tsums,
                                    int* __restrict__ row_ptr, float* __restrict__ norm,
                                    float* __restrict__ nsq, int n, int e_total) {
    int t = blockIdx.x * blockDim.x + threadIdx.x;
    int chunk = (n + SCAN_THREADS - 1) / SCAN_THREADS;
    int beg = t * chunk, end = min(beg + chunk, n);
    int run = tsums[t];
    for (int i = beg; i < end; ++i) {
        row_ptr[i] = run;
        int d = deg[i];
        run += d;
        float dc = (float)max(d, 1);
        norm[i] = rsqrtf(dc);
        nsq[i]  = 0.9f / dc;          // 0.9 * norm^2, exact
    }
    if (t == 0) row_ptr[n] = e_total;
}

// ---------------------------------------------------------------- bucket scatter
// 4B src only (weights are gone in the z-recurrence). Range [e_beg, e_end)
// so the launcher can split it into two dispatches.
__global__ void bucket_kernel(const int* __restrict__ src, const int* __restrict__ dst,
                              const int* __restrict__ row_ptr, int* __restrict__ fill,
                              int* __restrict__ src_sorted, int e_beg, int e_end) {
    int i = e_beg + blockIdx.x * blockDim.x + threadIdx.x;
    if (i < e_end) {
        int d = dst[i];
        int pos = row_ptr[d] + atomicAdd(&fill[d], 1);
        src_sorted[pos] = src[i];
    }
}

// ------------------------------------------------- seed: z0 = norm * feat (fp16)
__global__ void seed_kernel(const float* __restrict__ feat, const float* __restrict__ norm,
                            __half* __restrict__ z0, int n16 /* n * 16 groups of 4 */) {
    int i = blockIdx.x * blockDim.x + threadIdx.x;
    if (i < n16) {
        const int node = i >> 4;                  // 16 float4-groups per row
        const float nn = norm[node];
        float4 v = reinterpret_cast<const float4*>(feat)[i];
        __half2 a = __floats2half2_rn(v.x * nn, v.y * nn);
        __half2 b = __floats2half2_rn(v.z * nn, v.w * nn);
        uint2 o;
        o.x = *reinterpret_cast<unsigned int*>(&a);
        o.y = *reinterpret_cast<unsigned int*>(&b);
        reinterpret_cast<uint2*>(z0)[i] = o;
    }
}

// ---------------------------------------------------------------- propagation
// 1 wave per node, fp16 z rows (128B): 8 lanes x 16B per row; 8 edge groups
// gather 8 edges concurrently. Inner loop is a pure gather-accumulate.
// Non-final: z_out = nsq[node]*acc + 0.1*z0row   (all in the z domain)
// Final:     out   = 0.9*norm[node]*acc + 0.1*feat0 (fp32)
template<bool FINAL>
__global__ __launch_bounds__(256) void propagate_kernel(
        const __half* __restrict__ z, const __half* __restrict__ z0,
        const float* __restrict__ feat0,
        const int* __restrict__ row_ptr, const int* __restrict__ src_sorted,
        const float* __restrict__ norm, const float* __restrict__ nsq,
        __half* __restrict__ out_z, float* __restrict__ out_f, int n) {
    const int node = blockIdx.x * 4 + (threadIdx.x >> 6);
    if (node >= n) return;
    const int lane = threadIdx.x & 63;
    const int g   = lane >> 3;   // edge group 0..7
    const int sub = lane & 7;    // 16B chunk within the 128B row

    const int beg = row_ptr[node];
    const int end = row_ptr[node + 1];

    float acc[8] = {0.f, 0.f, 0.f, 0.f, 0.f, 0.f, 0.f, 0.f};
    for (int e = beg + g; e < end; e += 8) {
        const int s = src_sorted[e];
        uint4 raw = *reinterpret_cast<const uint4*>(z + (size_t)s * D_FEAT + sub * 8);
        __half2 p0 = *reinterpret_cast<__half2*>(&raw.x);
        __half2 p1 = *reinterpret_cast<__half2*>(&raw.y);
        __half2 p2 = *reinterpret_cast<__half2*>(&raw.z);
        __half2 p3 = *reinterpret_cast<__half2*>(&raw.w);
        float2 f0 = __half22float2(p0), f1 = __half22float2(p1);
        float2 f2 = __half22float2(p2), f3 = __half22float2(p3);
        acc[0] += f0.x; acc[1] += f0.y;
        acc[2] += f1.x; acc[3] += f1.y;
        acc[4] += f2.x; acc[5] += f2.y;
        acc[6] += f3.x; acc[7] += f3.y;
    }

    // reduce the 8 per-group partials (lanes differing in bits 3..5)
    #pragma unroll
    for (int off = 8; off <= 32; off <<= 1) {
        #pragma unroll
        for (int i = 0; i < 8; ++i) acc[i] += __shfl_xor(acc[i], off);
    }

    if (g == 0) {
        const size_t base = (size_t)node * D_FEAT + sub * 8;
        if (FINAL) {
            const float s = 0.9f * norm[node];
            const float4 fa = *reinterpret_cast<const float4*>(feat0 + base);
            const float4 fb = *reinterpret_cast<const float4*>(feat0 + base + 4);
            float4 w0, w1;
            w0.x = s * acc[0] + ALPHA * fa.x;  w0.y = s * acc[1] + ALPHA * fa.y;
            w0.z = s * acc[2] + ALPHA * fa.z;  w0.w = s * acc[3] + ALPHA * fa.w;
            w1.x = s * acc[4] + ALPHA * fb.x;  w1.y = s * acc[5] + ALPHA * fb.y;
            w1.z = s * acc[6] + ALPHA * fb.z;  w1.w = s * acc[7] + ALPHA * fb.w;
            *reinterpret_cast<float4*>(out_f + base)     = w0;
            *reinterpret_cast<float4*>(out_f + base + 4) = w1;
        } else {
            const float s = nsq[node];           // 0.9 * norm^2
            uint4 raw = *reinterpret_cast<const uint4*>(z0 + base);
            __half2 q0 = *reinterpret_cast<__half2*>(&raw.x);
            __half2 q1 = *reinterpret_cast<__half2*>(&raw.y);
            __half2 q2 = *reinterpret_cast<__half2*>(&raw.z);
            __half2 q3 = *reinterpret_cast<__half2*>(&raw.w);
            float2 f0 = __half22float2(q0), f1 = __half22float2(q1);
            float2 f2 = __half22float2(q2), f3 = __half22float2(q3);
            float o[8];
            o[0] = s * acc[0] + ALPHA * f0.x;  o[1] = s * acc[1] + ALPHA * f0.y;
            o[2] = s * acc[2] + ALPHA * f1.x;  o[3] = s * acc[3] + ALPHA * f1.y;
            o[4] = s * acc[4] + ALPHA * f2.x;  o[5] = s * acc[5] + ALPHA * f2.y;
            o[6] = s * acc[6] + ALPHA * f3.x;  o[7] = s * acc[7] + ALPHA * f3.y;
            __half2 h0 = __floats2half2_rn(o[0], o[1]);
            __half2 h1 = __floats2half2_rn(o[2], o[3]);
            __half2 h2 = __floats2half2_rn(o[4], o[5]);
            __half2 h3 = __floats2half2_rn(o[6], o[7]);
            uint4 w;
            w.x = *reinterpret_cast<unsigned int*>(&h0);
            w.y = *reinterpret_cast<unsigned int*>(&h1);
            w.z = *reinterpret_cast<unsigned int*>(&h2);
            w.w = *reinterpret_cast<unsigned int*>(&h3);
            *reinterpret_cast<uint4*>(out_z + base) = w;
        }
    }
}

// ---------------------------------------------------------------- launcher
static inline size_t align_up(size_t x, size_t a) { return (x + a - 1) & ~(a - 1); }

extern "C" void kernel_launch(void* const* d_in, const int* in_sizes, int n_in,
                              void* d_out, int out_size, void* d_ws, size_t ws_size,
                              hipStream_t stream) {
    const float* feat     = (const float*)d_in[0];
    const int*   edge_src = (const int*)d_in[1];
    const int*   edge_dst = (const int*)d_in[2];
    float*       out      = (float*)d_out;

    const int n = in_sizes[0] / D_FEAT;   // 100000
    const int e = in_sizes[1];            // 1000000

    // ---- workspace layout (rebuilt every call; ws is poisoned) ----
    char* ws = (char*)d_ws;
    int*    deg        = (int*)ws;    ws += align_up((size_t)n * 4, 256);
    int*    row_ptr    = (int*)ws;    ws += align_up((size_t)(n + 1) * 4, 256);
    float*  norm       = (float*)ws;  ws += align_up((size_t)n * 4, 256);
    float*  nsq        = (float*)ws;  ws += align_up((size_t)n * 4, 256);
    int*    fill       = (int*)ws;    ws += align_up((size_t)n * 4, 256);
    int*    tsums      = (int*)ws;    ws += align_up((size_t)SCAN_THREADS * 4, 256);
    int*    src_sorted = (int*)ws;    ws += align_up((size_t)e * 4, 256);
    __half* z0         = (__half*)ws; ws += align_up((size_t)n * D_FEAT * 2, 256);
    __half* zA         = (__half*)ws; ws += align_up((size_t)n * D_FEAT * 2, 256);
    __half* zB         = (__half*)ws; ws += align_up((size_t)n * D_FEAT * 2, 256);

    hipMemsetAsync(deg,  0, (size_t)n * 4, stream);
    hipMemsetAsync(fill, 0, (size_t)n * 4, stream);

    const int eb = 256;
    count_deg_kernel<<<(e + eb - 1) / eb, eb, 0, stream>>>(edge_dst, deg, e);
    partial_sum_kernel<<<SCAN_BLOCKS, 256, 0, stream>>>(deg, tsums, n);
    scan_partials_kernel<<<1, 1024, 0, stream>>>(tsums);
    write_rowptr_kernel<<<SCAN_BLOCKS, 256, 0, stream>>>(deg, tsums, row_ptr, norm, nsq, n, e);

    // bucket scatter, split into 2 dispatches (also unmasks propagate in rocprof)
    const int eh = e / 2;
    bucket_kernel<<<(eh + eb - 1) / eb, eb, 0, stream>>>(edge_src, edge_dst, row_ptr, fill,
                                                         src_sorted, 0, eh);
    bucket_kernel<<<(e - eh + eb - 1) / eb, eb, 0, stream>>>(edge_src, edge_dst, row_ptr, fill,
                                                             src_sorted, eh, e);

    // seed: z0 = norm * feat (fp16)
    const int n16 = n * D_FEAT / 4;
    seed_kernel<<<(n16 + 255) / 256, 256, 0, stream>>>(feat, norm, z0, n16);

    // K iterations: it=1 reads z0; 2..9 ping-pong zA/zB; it=10 -> fp32 out.
    const int pg = (n + 3) / 4;
    const __half* z_in = z0;
    for (int it = 1; it < K_ITERS; ++it) {
        __half* z_out = (it & 1) ? zA : zB;
        propagate_kernel<false><<<pg, 256, 0, stream>>>(z_in, z0, nullptr, row_ptr, src_sorted,
                                                        norm, nsq, z_out, nullptr, n);
        z_in = z_out;
    }
    propagate_kernel<true><<<pg, 256, 0, stream>>>(z_in, z0, feat, row_ptr, src_sorted,
                                                   norm, nsq, nullptr, out, n);
}

// Round 16
// 581.821 us; speedup vs baseline: 1.0021x; 1.0021x over previous
//
#include <hip/hip_runtime.h>
#include <hip/hip_bf16.h>
#include <hip/hip_fp16.h>

// APPNP propagation on MI355X.
// R1:  parallel scan; float4 quarter-wave propagate.                690us
// R3:  fp16 intermediate h + 8-way edge parallelism.                586us
// R14: int2 bucket revert + fp16 feat0.                             582us
// R15: z-recurrence, 4B src scatter, pure gather-sum loop.          583us
// R16: unroll-2 gather (two independent uint4 loads in flight per group).
//      R15 counters proved fp16 propagate is MLP/latency-bound, not BW-bound:
//      fp32 version sustained 4.8 TB/s of random lines, fp16 only 3.05.

#define D_FEAT 64
#define K_ITERS 10
#define ALPHA 0.1f

#define SCAN_THREADS 4096   // 16 blocks x 256
#define SCAN_BLOCKS  16

// ---------------------------------------------------------------- degree count
__global__ void count_deg_kernel(const int* __restrict__ dst, int* __restrict__ deg, int e) {
    int i = blockIdx.x * blockDim.x + threadIdx.x;
    if (i < e) atomicAdd(&deg[dst[i]], 1);
}

// ------------------------------------------------------- scan stage 1: partials
__global__ void partial_sum_kernel(const int* __restrict__ deg, int* __restrict__ tsums, int n) {
    int t = blockIdx.x * blockDim.x + threadIdx.x;        // 0..4095
    int chunk = (n + SCAN_THREADS - 1) / SCAN_THREADS;
    int beg = t * chunk, end = min(beg + chunk, n);
    int s = 0;
    for (int i = beg; i < end; ++i) s += deg[i];
    tsums[t] = s;
}

// -------------------------------------------- scan stage 2: scan 4096 partials
__global__ void scan_partials_kernel(int* __restrict__ tsums) {
    __shared__ int part[1024];
    const int tid = threadIdx.x;
    int s0 = tsums[tid * 4 + 0], s1 = tsums[tid * 4 + 1];
    int s2 = tsums[tid * 4 + 2], s3 = tsums[tid * 4 + 3];
    int sum = s0 + s1 + s2 + s3;
    part[tid] = sum;
    __syncthreads();
    for (int off = 1; off < 1024; off <<= 1) {
        int t = (tid >= off) ? part[tid - off] : 0;
        __syncthreads();
        part[tid] += t;
        __syncthreads();
    }
    int ex = part[tid] - sum;
    tsums[tid * 4 + 0] = ex;
    tsums[tid * 4 + 1] = ex + s0;
    tsums[tid * 4 + 2] = ex + s0 + s1;
    tsums[tid * 4 + 3] = ex + s0 + s1 + s2;
}

// --------------------------------- scan stage 3: row_ptr + norm + 0.9*norm^2
__global__ void write_rowptr_kernel(const int* __restrict__ deg, const int* __restrict__ tsums,
                                    int* __restrict__ row_ptr, float* __restrict__ norm,
                                    float* __restrict__ nsq, int n, int e_total) {
    int t = blockIdx.x * blockDim.x + threadIdx.x;
    int chunk = (n + SCAN_THREADS - 1) / SCAN_THREADS;
    int beg = t * chunk, end = min(beg + chunk, n);
    int run = tsums[t];
    for (int i = beg; i < end; ++i) {
        row_ptr[i] = run;
        int d = deg[i];
        run += d;
        float dc = (float)max(d, 1);
        norm[i] = rsqrtf(dc);
        nsq[i]  = 0.9f / dc;          // 0.9 * norm^2, exact
    }
    if (t == 0) row_ptr[n] = e_total;
}

// ---------------------------------------------------------------- bucket scatter
__global__ void bucket_kernel(const int* __restrict__ src, const int* __restrict__ dst,
                              const int* __restrict__ row_ptr, int* __restrict__ fill,
                              int* __restrict__ src_sorted, int e_beg, int e_end) {
    int i = e_beg + blockIdx.x * blockDim.x + threadIdx.x;
    if (i < e_end) {
        int d = dst[i];
        int pos = row_ptr[d] + atomicAdd(&fill[d], 1);
        src_sorted[pos] = src[i];
    }
}

// ------------------------------------------------- seed: z0 = norm * feat (fp16)
__global__ void seed_kernel(const float* __restrict__ feat, const float* __restrict__ norm,
                            __half* __restrict__ z0, int n16 /* n * 16 groups of 4 */) {
    int i = blockIdx.x * blockDim.x + threadIdx.x;
    if (i < n16) {
        const int node = i >> 4;                  // 16 float4-groups per row
        const float nn = norm[node];
        float4 v = reinterpret_cast<const float4*>(feat)[i];
        __half2 a = __floats2half2_rn(v.x * nn, v.y * nn);
        __half2 b = __floats2half2_rn(v.z * nn, v.w * nn);
        uint2 o;
        o.x = *reinterpret_cast<unsigned int*>(&a);
        o.y = *reinterpret_cast<unsigned int*>(&b);
        reinterpret_cast<uint2*>(z0)[i] = o;
    }
}

__device__ __forceinline__ void acc_row(float* acc, uint4 raw) {
    __half2 p0 = *reinterpret_cast<__half2*>(&raw.x);
    __half2 p1 = *reinterpret_cast<__half2*>(&raw.y);
    __half2 p2 = *reinterpret_cast<__half2*>(&raw.z);
    __half2 p3 = *reinterpret_cast<__half2*>(&raw.w);
    float2 f0 = __half22float2(p0), f1 = __half22float2(p1);
    float2 f2 = __half22float2(p2), f3 = __half22float2(p3);
    acc[0] += f0.x; acc[1] += f0.y;
    acc[2] += f1.x; acc[3] += f1.y;
    acc[4] += f2.x; acc[5] += f2.y;
    acc[6] += f3.x; acc[7] += f3.y;
}

// ---------------------------------------------------------------- propagation
// 1 wave per node, fp16 z rows (128B): 8 groups x 8 lanes. Unroll-2: each
// group issues TWO independent gathers (edges e, e+8) back-to-back -> 16
// lines in flight per wave (matches the fp32 version's measured 4.8 TB/s).
template<bool FINAL>
__global__ __launch_bounds__(256) void propagate_kernel(
        const __half* __restrict__ z, const __half* __restrict__ z0,
        const float* __restrict__ feat0,
        const int* __restrict__ row_ptr, const int* __restrict__ src_sorted,
        const float* __restrict__ norm, const float* __restrict__ nsq,
        __half* __restrict__ out_z, float* __restrict__ out_f, int n) {
    const int node = blockIdx.x * 4 + (threadIdx.x >> 6);
    if (node >= n) return;
    const int lane = threadIdx.x & 63;
    const int g   = lane >> 3;   // edge group 0..7
    const int sub = lane & 7;    // 16B chunk within the 128B row

    const int beg = row_ptr[node];
    const int end = row_ptr[node + 1];

    float acc[8] = {0.f, 0.f, 0.f, 0.f, 0.f, 0.f, 0.f, 0.f};

    int e = beg + g;
    // main: two independent gathers per round
    for (; e + 8 < end; e += 16) {
        const int s0 = src_sorted[e];
        const int s1 = src_sorted[e + 8];
        uint4 r0 = *reinterpret_cast<const uint4*>(z + (size_t)s0 * D_FEAT + sub * 8);
        uint4 r1 = *reinterpret_cast<const uint4*>(z + (size_t)s1 * D_FEAT + sub * 8);
        acc_row(acc, r0);
        acc_row(acc, r1);
    }
    // tail: at most one edge left for this group
    if (e < end) {
        const int s = src_sorted[e];
        uint4 r = *reinterpret_cast<const uint4*>(z + (size_t)s * D_FEAT + sub * 8);
        acc_row(acc, r);
    }

    // reduce the 8 per-group partials (lanes differing in bits 3..5)
    #pragma unroll
    for (int off = 8; off <= 32; off <<= 1) {
        #pragma unroll
        for (int i = 0; i < 8; ++i) acc[i] += __shfl_xor(acc[i], off);
    }

    if (g == 0) {
        const size_t base = (size_t)node * D_FEAT + sub * 8;
        if (FINAL) {
            const float s = 0.9f * norm[node];
            const float4 fa = *reinterpret_cast<const float4*>(feat0 + base);
            const float4 fb = *reinterpret_cast<const float4*>(feat0 + base + 4);
            float4 w0, w1;
            w0.x = s * acc[0] + ALPHA * fa.x;  w0.y = s * acc[1] + ALPHA * fa.y;
            w0.z = s * acc[2] + ALPHA * fa.z;  w0.w = s * acc[3] + ALPHA * fa.w;
            w1.x = s * acc[4] + ALPHA * fb.x;  w1.y = s * acc[5] + ALPHA * fb.y;
            w1.z = s * acc[6] + ALPHA * fb.z;  w1.w = s * acc[7] + ALPHA * fb.w;
            *reinterpret_cast<float4*>(out_f + base)     = w0;
            *reinterpret_cast<float4*>(out_f + base + 4) = w1;
        } else {
            const float s = nsq[node];           // 0.9 * norm^2
            uint4 raw = *reinterpret_cast<const uint4*>(z0 + base);
            __half2 q0 = *reinterpret_cast<__half2*>(&raw.x);
            __half2 q1 = *reinterpret_cast<__half2*>(&raw.y);
            __half2 q2 = *reinterpret_cast<__half2*>(&raw.z);
            __half2 q3 = *reinterpret_cast<__half2*>(&raw.w);
            float2 f0 = __half22float2(q0), f1 = __half22float2(q1);
            float2 f2 = __half22float2(q2), f3 = __half22float2(q3);
            float o[8];
            o[0] = s * acc[0] + ALPHA * f0.x;  o[1] = s * acc[1] + ALPHA * f0.y;
            o[2] = s * acc[2] + ALPHA * f1.x;  o[3] = s * acc[3] + ALPHA * f1.y;
            o[4] = s * acc[4] + ALPHA * f2.x;  o[5] = s * acc[5] + ALPHA * f2.y;
            o[6] = s * acc[6] + ALPHA * f3.x;  o[7] = s * acc[7] + ALPHA * f3.y;
            __half2 h0 = __floats2half2_rn(o[0], o[1]);
            __half2 h1 = __floats2half2_rn(o[2], o[3]);
            __half2 h2 = __floats2half2_rn(o[4], o[5]);
            __half2 h3 = __floats2half2_rn(o[6], o[7]);
            uint4 w;
            w.x = *reinterpret_cast<unsigned int*>(&h0);
            w.y = *reinterpret_cast<unsigned int*>(&h1);
            w.z = *reinterpret_cast<unsigned int*>(&h2);
            w.w = *reinterpret_cast<unsigned int*>(&h3);
            *reinterpret_cast<uint4*>(out_z + base) = w;
        }
    }
}

// ---------------------------------------------------------------- launcher
static inline size_t align_up(size_t x, size_t a) { return (x + a - 1) & ~(a - 1); }

extern "C" void kernel_launch(void* const* d_in, const int* in_sizes, int n_in,
                              void* d_out, int out_size, void* d_ws, size_t ws_size,
                              hipStream_t stream) {
    const float* feat     = (const float*)d_in[0];
    const int*   edge_src = (const int*)d_in[1];
    const int*   edge_dst = (const int*)d_in[2];
    float*       out      = (float*)d_out;

    const int n = in_sizes[0] / D_FEAT;   // 100000
    const int e = in_sizes[1];            // 1000000

    // ---- workspace layout (rebuilt every call; ws is poisoned) ----
    char* ws = (char*)d_ws;
    int*    deg        = (int*)ws;    ws += align_up((size_t)n * 4, 256);
    int*    row_ptr    = (int*)ws;    ws += align_up((size_t)(n + 1) * 4, 256);
    float*  norm       = (float*)ws;  ws += align_up((size_t)n * 4, 256);
    float*  nsq        = (float*)ws;  ws += align_up((size_t)n * 4, 256);
    int*    fill       = (int*)ws;    ws += align_up((size_t)n * 4, 256);
    int*    tsums      = (int*)ws;    ws += align_up((size_t)SCAN_THREADS * 4, 256);
    int*    src_sorted = (int*)ws;    ws += align_up((size_t)e * 4, 256);
    __half* z0         = (__half*)ws; ws += align_up((size_t)n * D_FEAT * 2, 256);
    __half* zA         = (__half*)ws; ws += align_up((size_t)n * D_FEAT * 2, 256);
    __half* zB         = (__half*)ws; ws += align_up((size_t)n * D_FEAT * 2, 256);

    hipMemsetAsync(deg,  0, (size_t)n * 4, stream);
    hipMemsetAsync(fill, 0, (size_t)n * 4, stream);

    const int eb = 256;
    count_deg_kernel<<<(e + eb - 1) / eb, eb, 0, stream>>>(edge_dst, deg, e);
    partial_sum_kernel<<<SCAN_BLOCKS, 256, 0, stream>>>(deg, tsums, n);
    scan_partials_kernel<<<1, 1024, 0, stream>>>(tsums);
    write_rowptr_kernel<<<SCAN_BLOCKS, 256, 0, stream>>>(deg, tsums, row_ptr, norm, nsq, n, e);

    // bucket scatter, split into 2 dispatches (keeps propagate visible in rocprof)
    const int eh = e / 2;
    bucket_kernel<<<(eh + eb - 1) / eb, eb, 0, stream>>>(edge_src, edge_dst, row_ptr, fill,
                                                         src_sorted, 0, eh);
    bucket_kernel<<<(e - eh + eb - 1) / eb, eb, 0, stream>>>(edge_src, edge_dst, row_ptr, fill,
                                                             src_sorted, eh, e);

    // seed: z0 = norm * feat (fp16)
    const int n16 = n * D_FEAT / 4;
    seed_kernel<<<(n16 + 255) / 256, 256, 0, stream>>>(feat, norm, z0, n16);

    // K iterations: it=1 reads z0; 2..9 ping-pong zA/zB; it=10 -> fp32 out.
    const int pg = (n + 3) / 4;
    const __half* z_in = z0;
    for (int it = 1; it < K_ITERS; ++it) {
        __half* z_out = (it & 1) ? zA : zB;
        propagate_kernel<false><<<pg, 256, 0, stream>>>(z_in, z0, nullptr, row_ptr, src_sorted,
                                                        norm, nsq, z_out, nullptr, n);
        z_in = z_out;
    }
    propagate_kernel<true><<<pg, 256, 0, stream>>>(z_in, z0, feat, row_ptr, src_sorted,
                                                   norm, nsq, nullptr, out, n);
}